// Round 13
// baseline (367.120 us; speedup 1.0000x reference)
//
#include <hip/hip_runtime.h>
#include <math.h>

// DCGRU cell, N=8192, B=1, D_IN=2, UNITS=64, K=2 -> F=66, M=3.
// MEASUREMENT ROUND: identical to the R11 kernel (289 us) except k_conv is
// launched TWICE (idempotent: adjF/dpart are pure functions of adj).
// dur_us - 289 ~= one k_conv duration -> resolves conv-vs-hops attribution
// that the poison-fill-polluted top-5 profile cannot.

typedef __attribute__((ext_vector_type(8))) short short8v;
typedef __attribute__((ext_vector_type(4))) float f32x4;

constexpr int NN  = 8192;
constexpr int CST = 80;
constexpr int KBT = 256;
constexpr int MCH = 4;
constexpr size_t NS   = (size_t)NN * CST;
constexpr size_t UTFS = (size_t)KBT * 5 * 512;

static __device__ __forceinline__ ushort f2bf(float x) {
  union { float f; unsigned u; } c; c.f = x;
  unsigned u = c.u;
  u += 0x7fffu + ((u >> 16) & 1u);               // RNE
  return (ushort)(u >> 16);
}

static __device__ __forceinline__ void mfma_b16(f32x4& acc, short8v a, short8v b) {
  asm("v_mfma_f32_16x16x32_bf16 %0, %1, %2, %0" : "+v"(acc) : "v"(a), "v"(b));
}

// ---------------- adj -> bf16 fragment transpose + row-sum partials ----------
__global__ __launch_bounds__(256, 4) void k_conv(const float* __restrict__ adj,
                                                 ushort* __restrict__ adjF,
                                                 float* __restrict__ dpart) {
  __shared__ float tile[2][32][132];
  const int kb = blockIdx.x, mc = blockIdx.y;
  const int tid = threadIdx.x;
  const int l = tid & 63, w = tid >> 6;
  const int rg = tid >> 5;
  const int cb = (tid & 31) * 4;
  const float* src = adj + ((size_t)kb * 32 + rg) * NN + (size_t)mc * 2048 + cb;
  float rs[4] = {0.f, 0.f, 0.f, 0.f};
  float4 vA[4], vB[4];

#pragma unroll
  for (int i = 0; i < 4; ++i)
    vA[i] = *(const float4*)(src + (size_t)(8 * i) * NN);

#define CONV_BODY(CH, BUF, VC, VN)                                             \
  {                                                                            \
    const int ch_ = (CH);                                                      \
    _Pragma("unroll") for (int i = 0; i < 4; ++i) {                            \
      int r = rg + 8 * i;                                                      \
      int colp = (cb + 8 * i) & 127;                                           \
      *(float4*)&tile[BUF][r][colp] = VC[i];                                   \
      rs[i] += (VC[i].x + VC[i].y) + (VC[i].z + VC[i].w);                      \
    }                                                                          \
    if (ch_ < 15) {                                                            \
      _Pragma("unroll") for (int i = 0; i < 4; ++i)                            \
          VN[i] = *(const float4*)(src + (size_t)(8 * i) * NN + (ch_ + 1) * 128); \
    }                                                                          \
    __syncthreads();                                                           \
    _Pragma("unroll") for (int h = 0; h < 2; ++h) {                            \
      int fl = w + 4 * h;                                                      \
      int mt = mc * 128 + ch_ * 8 + fl;                                        \
      short8v o;                                                               \
      _Pragma("unroll") for (int j = 0; j < 8; ++j) {                          \
        int r = 8 * (l >> 4) + j;                                              \
        int colp = (fl * 16 + (l & 15) + 8 * (l >> 4)) & 127;                  \
        o[j] = (short)f2bf(tile[BUF][r][colp]);                                \
      }                                                                        \
      *(short8v*)(adjF + ((size_t)mt * KBT + kb) * 512 + l * 8) = o;           \
    }                                                                          \
  }

  for (int cp = 0; cp < 8; ++cp) {
    CONV_BODY(2 * cp,     0, vA, vB);
    CONV_BODY(2 * cp + 1, 1, vB, vA);
  }
#undef CONV_BODY

#pragma unroll
  for (int i = 0; i < 4; ++i) {
#pragma unroll
    for (int m = 16; m >= 1; m >>= 1) rs[i] += __shfl_xor(rs[i], m);
  }
  if ((tid & 31) == 0) {
#pragma unroll
    for (int i = 0; i < 4; ++i)
      dpart[(size_t)mc * NN + kb * 32 + 8 * i + rg] = rs[i];
  }
}

// ---------------- build: dinv + X0 + XS0 + UtFa ------------------------------
__global__ __launch_bounds__(256) void k_build(const float* __restrict__ hx,
                                               const float* __restrict__ inp,
                                               const float* __restrict__ dpart,
                                               float* __restrict__ dinv,
                                               float* __restrict__ X0,
                                               float* __restrict__ XS0,
                                               ushort* __restrict__ UtF) {
  __shared__ float dv_s[32];
  const int n0 = blockIdx.x * 32;
  const int tid = threadIdx.x;
  if (tid < 32) {
    int n = n0 + tid;
    float dv = 1.f / (dpart[n] + dpart[NN + n] + dpart[2 * NN + n] +
                      dpart[3 * NN + n] + 1.f);
    dv_s[tid] = dv;
    dinv[n] = dv;
  }
  __syncthreads();
  for (int p = tid; p < 32 * 20; p += 256) {
    int nl = p / 20, c4 = (p % 20) * 4;
    int n = n0 + nl;
    float dv = dv_s[nl];
    float v[4];
#pragma unroll
    for (int j = 0; j < 4; ++j) {
      int c = c4 + j;
      v[j] = (c < 64) ? hx[n * 64 + c] : (c < 66 ? inp[n * 2 + (c - 64)] : 0.f);
    }
    size_t o = (size_t)n * CST + c4;
    *(float4*)(X0 + o)  = make_float4(v[0], v[1], v[2], v[3]);
    *(float4*)(XS0 + o) = make_float4(dv * v[0], dv * v[1], dv * v[2], dv * v[3]);
  }
  for (int p = tid; p < 5 * 64; p += 256) {
    int nt = p >> 6, l = p & 63;
    short8v o8;
#pragma unroll
    for (int j = 0; j < 8; ++j) {
      int nloc = 8 * (l >> 4) + j;
      int n = n0 + nloc;
      int c = nt * 16 + (l & 15);
      float v = (c < 64) ? hx[n * 64 + c] : (c < 66 ? inp[n * 2 + (c - 64)] : 0.f);
      o8[j] = (short)f2bf(v * dv_s[nloc]);
    }
    *(short8v*)(UtF + ((size_t)blockIdx.x * 5 + nt) * 512 + l * 8) = o8;
  }
}

// ---------------- GEMM core: 4-wave K-split, E/O pipeline, LDS reduce --------
// Leaves sv[i] = full-K dot for item p = tid + i*256 of the 16x80 tile.
static __device__ __forceinline__ void gemm_core(const ushort* __restrict__ adjF,
                                                 const ushort* __restrict__ bF,
                                                 int mt, int tid, float* smem,
                                                 float sv[5]) {
  const int w = tid >> 6, l = tid & 63;
  f32x4 acc[5];
#pragma unroll
  for (int nt = 0; nt < 5; ++nt) acc[nt] = (f32x4){0.f, 0.f, 0.f, 0.f};
  const ushort* ap = adjF + ((size_t)mt * KBT + w * 64) * 512 + l * 8;
  const ushort* bp = bF + (size_t)(w * 64) * 5 * 512 + l * 8;

  short8v aE, aO, bE[5], bO[5];
  aE = *(const short8v*)(ap);
#pragma unroll
  for (int nt = 0; nt < 5; ++nt) bE[nt] = *(const short8v*)(bp + nt * 512);
  for (int kb = 0; kb < 64; kb += 2) {
    aO = *(const short8v*)(ap + (size_t)(kb + 1) * 512);
#pragma unroll
    for (int nt = 0; nt < 5; ++nt)
      bO[nt] = *(const short8v*)(bp + (size_t)((kb + 1) * 5 + nt) * 512);
#pragma unroll
    for (int nt = 0; nt < 5; ++nt) mfma_b16(acc[nt], aE, bE[nt]);
    aE = *(const short8v*)(ap + (size_t)(kb + 2) * 512);
#pragma unroll
    for (int nt = 0; nt < 5; ++nt)
      bE[nt] = *(const short8v*)(bp + (size_t)((kb + 2) * 5 + nt) * 512);
#pragma unroll
    for (int nt = 0; nt < 5; ++nt) mfma_b16(acc[nt], aO, bO[nt]);
  }
  asm volatile("s_nop 7\n\ts_nop 7\n\ts_nop 7" ::: "memory");

  auto red = reinterpret_cast<float(*)[64][20]>(smem);     // [w][l][20] = 20 KB
#pragma unroll
  for (int nt = 0; nt < 5; ++nt)
    *(f32x4*)&red[w][l][nt * 4] = acc[nt];
  __syncthreads();
#pragma unroll
  for (int i = 0; i < 5; ++i) {
    int p = tid + i * 256;
    int r = p / 80, c = p % 80;
    int ll = ((r >> 2) << 4) | (c & 15);
    int k  = ((c >> 4) << 2) | (r & 3);
    sv[i] = ((red[0][ll][k] + red[1][ll][k]) + red[2][ll][k]) + red[3][ll][k];
  }
  __syncthreads();                                         // smem reusable
}

// ---------------- hop1: X1 = A^T@XSin + XSin ; XS1 = dinv*X1 ; UtFout --------
__global__ __launch_bounds__(256, 2) void k_hop1(const ushort* __restrict__ adjF,
                                                 const ushort* __restrict__ UtFin,
                                                 const float* __restrict__ XSin,
                                                 const float* __restrict__ dinv,
                                                 float* __restrict__ X1,
                                                 float* __restrict__ XS1,
                                                 ushort* __restrict__ UtFout) {
  __shared__ __align__(16) float smem[5120];
  const int mt = blockIdx.x, tid = threadIdx.x;
  const int n0 = mt * 16;
  float sv[5];
  gemm_core(adjF, UtFin, mt, tid, smem, sv);

  auto xs = reinterpret_cast<float(*)[80]>(smem);
#pragma unroll
  for (int i = 0; i < 5; ++i) {
    int p = tid + i * 256;
    size_t o = (size_t)n0 * CST + p;
    float x1 = XSin[o] + sv[i];
    X1[o] = x1;
    float z = dinv[n0 + p / 80] * x1;
    XS1[o] = z;
    xs[p / 80][p % 80] = z;
  }
  __syncthreads();
  const int K = mt >> 1, g0 = (mt & 1) * 2;
  for (int p = tid; p < 5 * 32; p += 256) {
    int nt = p >> 5, idx = p & 31;
    int l2 = g0 * 16 + idx;
    short8v o8;
#pragma unroll
    for (int j = 0; j < 8; ++j)
      o8[j] = (short)f2bf(xs[8 * (idx >> 4) + j][nt * 16 + (idx & 15)]);
    *(short8v*)(UtFout + ((size_t)K * 5 + nt) * 512 + l2 * 8) = o8;
  }
}

// ---------------- hop2+gates: X2 in LDS; sigmoid matmul; X0:=rh etc. ---------
__global__ __launch_bounds__(256, 2) void k_hop2g(const ushort* __restrict__ adjF,
    const ushort* __restrict__ UtFb, const float* __restrict__ XS1,
    const float* __restrict__ X0, const float* __restrict__ X1,
    const float* __restrict__ w_ru, const float* __restrict__ b_ru,
    const float* __restrict__ hx, const float* __restrict__ inp,
    const float* __restrict__ dinv,
    float* __restrict__ X0w, float* __restrict__ XS0w,
    ushort* __restrict__ UtFa, float* __restrict__ UG) {
  __shared__ __align__(16) float smem[5120];
  const int mt = blockIdx.x, tid = threadIdx.x;
  const int n0 = mt * 16;
  float sv[5];
  gemm_core(adjF, UtFb, mt, tid, smem, sv);

  auto xr2 = reinterpret_cast<float(*)[80]>(smem);        // [16][80]
  float* xr01 = smem + 1280;                              // [2][16][68]
  float* rhq  = smem + 1280 + 2176;                       // [16][64]
#pragma unroll
  for (int i = 0; i < 5; ++i) {
    int p = tid + i * 256;
    size_t o = (size_t)n0 * CST + p;
    xr2[p / 80][p % 80] = 2.f * (XS1[o] + sv[i]) - X0[o];
  }
  for (int p = tid; p < 16 * 17; p += 256) {
    int nl = p / 17, c4 = (p % 17) * 4;
    size_t o = (size_t)(n0 + nl) * CST + c4;
    *(float4*)&xr01[nl * 68 + c4]            = *(const float4*)(X0 + o);
    *(float4*)&xr01[16 * 68 + nl * 68 + c4]  = *(const float4*)(X1 + o);
  }
  __syncthreads();

  const int nl = tid >> 4, og = tid & 15, o0 = og * 8;
  float acc[8];
#pragma unroll
  for (int j = 0; j < 8; ++j) acc[j] = b_ru[o0 + j];
  for (int c = 0; c < 66; ++c) {
    int f = (c < 64) ? (c + 2) : (c - 64);
    const float* wr = w_ru + (size_t)(f * 3) * 128 + o0;
    float xv[3];
    xv[0] = xr01[nl * 68 + c];
    xv[1] = xr01[16 * 68 + nl * 68 + c];
    xv[2] = xr2[nl][c];
#pragma unroll
    for (int m = 0; m < 3; ++m) {
      float wl[8];
      *(float4*)(wl)     = *(const float4*)(wr + m * 128);
      *(float4*)(wl + 4) = *(const float4*)(wr + m * 128 + 4);
#pragma unroll
      for (int j = 0; j < 8; ++j) acc[j] += xv[m] * wl[j];
    }
  }
  const int n = n0 + nl;
  const float dv = dinv[n];
  if (og < 8) {
#pragma unroll
    for (int j = 0; j < 8; ++j) {
      int o = o0 + j;
      float r = 1.f / (1.f + expf(-acc[j]));
      float rh = r * hx[n * 64 + o];
      X0w[(size_t)n * CST + o] = rh;
      float srh = dv * rh;
      XS0w[(size_t)n * CST + o] = srh;
      rhq[nl * 64 + o] = srh;
    }
  } else {
#pragma unroll
    for (int j = 0; j < 8; ++j)
      UG[n * 64 + (o0 - 64) + j] = 1.f / (1.f + expf(-acc[j]));
  }
  __syncthreads();
  const int K = mt >> 1, g0 = (mt & 1) * 2;
  for (int p = tid; p < 5 * 32; p += 256) {
    int nt = p >> 5, idx = p & 31;
    int l2 = g0 * 16 + idx;
    short8v o8;
#pragma unroll
    for (int j = 0; j < 8; ++j) {
      int lr = 8 * (idx >> 4) + j;
      int nn = n0 + lr;
      int c = nt * 16 + (idx & 15);
      float v;
      if (c < 64)      v = rhq[lr * 64 + c];
      else if (c < 66) v = dinv[nn] * inp[nn * 2 + (c - 64)];
      else             v = 0.f;
      o8[j] = (short)f2bf(v);
    }
    *(short8v*)(UtFa + ((size_t)K * 5 + nt) * 512 + l2 * 8) = o8;
  }
}

// ---------------- hop2+final: X2 in LDS; tanh matmul; output -----------------
__global__ __launch_bounds__(256, 2) void k_hop2f(const ushort* __restrict__ adjF,
    const ushort* __restrict__ UtFb, const float* __restrict__ XS1,
    const float* __restrict__ X0, const float* __restrict__ X1,
    const float* __restrict__ w_c, const float* __restrict__ b_c,
    const float* __restrict__ hx, const float* __restrict__ UG,
    float* __restrict__ out) {
  __shared__ __align__(16) float smem[5120];
  const int mt = blockIdx.x, tid = threadIdx.x;
  const int n0 = mt * 16;
  float sv[5];
  gemm_core(adjF, UtFb, mt, tid, smem, sv);

  auto xr2 = reinterpret_cast<float(*)[80]>(smem);        // [16][80]
  float* xr01 = smem + 1280;                              // [2][16][68]
#pragma unroll
  for (int i = 0; i < 5; ++i) {
    int p = tid + i * 256;
    size_t o = (size_t)n0 * CST + p;
    xr2[p / 80][p % 80] = 2.f * (XS1[o] + sv[i]) - X0[o];
  }
  for (int p = tid; p < 16 * 17; p += 256) {
    int nl = p / 17, c4 = (p % 17) * 4;
    size_t o = (size_t)(n0 + nl) * CST + c4;
    *(float4*)&xr01[nl * 68 + c4]           = *(const float4*)(X0 + o);
    *(float4*)&xr01[16 * 68 + nl * 68 + c4] = *(const float4*)(X1 + o);
  }
  __syncthreads();

  const int nl = tid >> 4, ot = tid & 15, o0 = ot * 4;
  float acc[4];
#pragma unroll
  for (int j = 0; j < 4; ++j) acc[j] = b_c[o0 + j];
  for (int c = 0; c < 66; ++c) {
    int f = (c < 64) ? (c + 2) : (c - 64);
    float xv[3];
    xv[0] = xr01[nl * 68 + c];
    xv[1] = xr01[16 * 68 + nl * 68 + c];
    xv[2] = xr2[nl][c];
#pragma unroll
    for (int m = 0; m < 3; ++m) {
      float wl[4];
      *(float4*)(wl) = *(const float4*)(w_c + (size_t)(f * 3 + m) * 64 + o0);
#pragma unroll
      for (int j = 0; j < 4; ++j) acc[j] += xv[m] * wl[j];
    }
  }
  const int n = n0 + nl;
#pragma unroll
  for (int j = 0; j < 4; ++j) {
    int o = o0 + j;
    float cc = tanhf(acc[j]);
    float u = UG[n * 64 + o];
    float h = hx[n * 64 + o];
    out[n * 64 + o] = u * h + (1.f - u) * cc;
  }
}

// ---------------- launcher ----------------------------------------------------
extern "C" void kernel_launch(void* const* d_in, const int* in_sizes, int n_in,
                              void* d_out, int out_size, void* d_ws, size_t ws_size,
                              hipStream_t stream) {
  const float* inp  = (const float*)d_in[0];
  const float* hx   = (const float*)d_in[1];
  const float* adj  = (const float*)d_in[2];
  const float* w_ru = (const float*)d_in[3];
  const float* b_ru = (const float*)d_in[4];
  const float* w_c  = (const float*)d_in[5];
  const float* b_c  = (const float*)d_in[6];
  float* out = (float*)d_out;

  float* ws    = (float*)d_ws;
  float* dinv  = ws;                          // 8192
  float* dpart = ws + 8192;                   // 4*8192
  float* X0    = ws + 8192 + 4 * 8192;        // [N][80] each
  float* XS0   = X0 + NS;
  float* X1    = XS0 + NS;
  float* XS1   = X1 + NS;
  ushort* UtFa = (ushort*)(XS1 + NS);         // 1.25 MB
  ushort* UtFb = UtFa + UTFS;                 // 1.25 MB
  ushort* adjF = UtFb + UTFS;                 // 128 MB
  float*  UG   = (float*)(adjF + (size_t)512 * KBT * 512);  // [N][64] + OOB pad

  dim3 cg(KBT, MCH);

  // MEASUREMENT: conv launched twice (idempotent). dur_us - 289 ~= conv time.
  k_conv <<<cg, 256, 0, stream>>>(adj, adjF, dpart);
  k_conv <<<cg, 256, 0, stream>>>(adj, adjF, dpart);
  k_build<<<NN / 32, 256, 0, stream>>>(hx, inp, dpart, dinv, X0, XS0, UtFa);

  // gconv 1 (gates)
  k_hop1 <<<512, 256, 0, stream>>>(adjF, UtFa, XS0, dinv, X1, XS1, UtFb);
  k_hop2g<<<512, 256, 0, stream>>>(adjF, UtFb, XS1, X0, X1, w_ru, b_ru, hx, inp,
                                   dinv, X0, XS0, UtFa, UG);

  // gconv 2 (candidate)
  k_hop1 <<<512, 256, 0, stream>>>(adjF, UtFa, XS0, dinv, X1, XS1, UtFb);
  k_hop2f<<<512, 256, 0, stream>>>(adjF, UtFb, XS1, X0, X1, w_c, b_c, hx, UG, out);
}

// Round 14
// 286.403 us; speedup vs baseline: 1.2818x; 1.2818x over previous
//
#include <hip/hip_runtime.h>
#include <math.h>

// DCGRU cell, N=8192, B=1, D_IN=2, UNITS=64, K=2 -> F=66, M=3.
// adj_mx @ v == adj^T @ (dinv*v) + (dinv*v)   (adj2 = adj + I folded in)
// 6 launches: k_conv -> k_build -> k_hop1 -> k_hop2g -> k_hop1 -> k_hop2f
// Hop kernels (512 thr / 8 waves, grid 256): block owns TWO mt tiles (32 rows);
// wave w does K-chunk w*32 kb for BOTH mt (shared B loads -> L2 B-traffic
// halved vs R11); E/O depth-2; two-stage LDS reduce; epilogue inline.
// ws order ...UtFa,UtFb,adjF,UG so branchless prefetch over-reads are harmless.

typedef __attribute__((ext_vector_type(8))) short short8v;
typedef __attribute__((ext_vector_type(4))) float f32x4;

constexpr int NN  = 8192;
constexpr int CST = 80;
constexpr int KBT = 256;
constexpr int MCH = 4;
constexpr size_t NS   = (size_t)NN * CST;
constexpr size_t UTFS = (size_t)KBT * 5 * 512;

static __device__ __forceinline__ ushort f2bf(float x) {
  union { float f; unsigned u; } c; c.f = x;
  unsigned u = c.u;
  u += 0x7fffu + ((u >> 16) & 1u);               // RNE
  return (ushort)(u >> 16);
}

static __device__ __forceinline__ void mfma_b16(f32x4& acc, short8v a, short8v b) {
  asm("v_mfma_f32_16x16x32_bf16 %0, %1, %2, %0" : "+v"(acc) : "v"(a), "v"(b));
}

// ---------------- adj -> bf16 fragment transpose + row-sum partials ----------
__global__ __launch_bounds__(256, 4) void k_conv(const float* __restrict__ adj,
                                                 ushort* __restrict__ adjF,
                                                 float* __restrict__ dpart) {
  __shared__ float tile[2][32][132];
  const int kb = blockIdx.x, mc = blockIdx.y;
  const int tid = threadIdx.x;
  const int l = tid & 63, w = tid >> 6;
  const int rg = tid >> 5;
  const int cb = (tid & 31) * 4;
  const float* src = adj + ((size_t)kb * 32 + rg) * NN + (size_t)mc * 2048 + cb;
  float rs[4] = {0.f, 0.f, 0.f, 0.f};
  float4 vA[4], vB[4];

#pragma unroll
  for (int i = 0; i < 4; ++i)
    vA[i] = *(const float4*)(src + (size_t)(8 * i) * NN);

#define CONV_BODY(CH, BUF, VC, VN)                                             \
  {                                                                            \
    const int ch_ = (CH);                                                      \
    _Pragma("unroll") for (int i = 0; i < 4; ++i) {                            \
      int r = rg + 8 * i;                                                      \
      int colp = (cb + 8 * i) & 127;                                           \
      *(float4*)&tile[BUF][r][colp] = VC[i];                                   \
      rs[i] += (VC[i].x + VC[i].y) + (VC[i].z + VC[i].w);                      \
    }                                                                          \
    if (ch_ < 15) {                                                            \
      _Pragma("unroll") for (int i = 0; i < 4; ++i)                            \
          VN[i] = *(const float4*)(src + (size_t)(8 * i) * NN + (ch_ + 1) * 128); \
    }                                                                          \
    __syncthreads();                                                           \
    _Pragma("unroll") for (int h = 0; h < 2; ++h) {                            \
      int fl = w + 4 * h;                                                      \
      int mt = mc * 128 + ch_ * 8 + fl;                                        \
      short8v o;                                                               \
      _Pragma("unroll") for (int j = 0; j < 8; ++j) {                          \
        int r = 8 * (l >> 4) + j;                                              \
        int colp = (fl * 16 + (l & 15) + 8 * (l >> 4)) & 127;                  \
        o[j] = (short)f2bf(tile[BUF][r][colp]);                                \
      }                                                                        \
      *(short8v*)(adjF + ((size_t)mt * KBT + kb) * 512 + l * 8) = o;           \
    }                                                                          \
  }

  for (int cp = 0; cp < 8; ++cp) {
    CONV_BODY(2 * cp,     0, vA, vB);
    CONV_BODY(2 * cp + 1, 1, vB, vA);
  }
#undef CONV_BODY

#pragma unroll
  for (int i = 0; i < 4; ++i) {
#pragma unroll
    for (int m = 16; m >= 1; m >>= 1) rs[i] += __shfl_xor(rs[i], m);
  }
  if ((tid & 31) == 0) {
#pragma unroll
    for (int i = 0; i < 4; ++i)
      dpart[(size_t)mc * NN + kb * 32 + 8 * i + rg] = rs[i];
  }
}

// ---------------- build: dinv + X0 + XS0 + UtFa ------------------------------
__global__ __launch_bounds__(256) void k_build(const float* __restrict__ hx,
                                               const float* __restrict__ inp,
                                               const float* __restrict__ dpart,
                                               float* __restrict__ dinv,
                                               float* __restrict__ X0,
                                               float* __restrict__ XS0,
                                               ushort* __restrict__ UtF) {
  __shared__ float dv_s[32];
  const int n0 = blockIdx.x * 32;
  const int tid = threadIdx.x;
  if (tid < 32) {
    int n = n0 + tid;
    float dv = 1.f / (dpart[n] + dpart[NN + n] + dpart[2 * NN + n] +
                      dpart[3 * NN + n] + 1.f);
    dv_s[tid] = dv;
    dinv[n] = dv;
  }
  __syncthreads();
  for (int p = tid; p < 32 * 20; p += 256) {
    int nl = p / 20, c4 = (p % 20) * 4;
    int n = n0 + nl;
    float dv = dv_s[nl];
    float v[4];
#pragma unroll
    for (int j = 0; j < 4; ++j) {
      int c = c4 + j;
      v[j] = (c < 64) ? hx[n * 64 + c] : (c < 66 ? inp[n * 2 + (c - 64)] : 0.f);
    }
    size_t o = (size_t)n * CST + c4;
    *(float4*)(X0 + o)  = make_float4(v[0], v[1], v[2], v[3]);
    *(float4*)(XS0 + o) = make_float4(dv * v[0], dv * v[1], dv * v[2], dv * v[3]);
  }
  for (int p = tid; p < 5 * 64; p += 256) {
    int nt = p >> 6, l = p & 63;
    short8v o8;
#pragma unroll
    for (int j = 0; j < 8; ++j) {
      int nloc = 8 * (l >> 4) + j;
      int n = n0 + nloc;
      int c = nt * 16 + (l & 15);
      float v = (c < 64) ? hx[n * 64 + c] : (c < 66 ? inp[n * 2 + (c - 64)] : 0.f);
      o8[j] = (short)f2bf(v * dv_s[nloc]);
    }
    *(short8v*)(UtF + ((size_t)blockIdx.x * 5 + nt) * 512 + l * 8) = o8;
  }
}

// ---------------- GEMM core: 8-wave K-split, 2 mt per wave, shared B ---------
// Block bid owns mt = 2*bid, 2*bid+1 (rows n0..n0+31). Wave w: kb chunk w*32.
// Leaves sv[i] = full-K dot for item p = tid + i*512 of the 32x80 tile.
static __device__ __forceinline__ void gemm_core2(const ushort* __restrict__ adjF,
                                                  const ushort* __restrict__ bF,
                                                  int bid, int tid, float* smem,
                                                  float sv[5]) {
  const int w8 = tid >> 6, l = tid & 63;
  const int kbase = w8 * 32;
  f32x4 acc0[5], acc1[5];
#pragma unroll
  for (int nt = 0; nt < 5; ++nt) {
    acc0[nt] = (f32x4){0.f, 0.f, 0.f, 0.f};
    acc1[nt] = (f32x4){0.f, 0.f, 0.f, 0.f};
  }
  const ushort* ap = adjF + ((size_t)(2 * bid) * KBT + kbase) * 512 + l * 8;
  const size_t MSTR = (size_t)KBT * 512;          // adjF stride between mt
  const ushort* bp = bF + (size_t)kbase * 5 * 512 + l * 8;

  short8v aE0, aE1, aO0, aO1, bE[5], bO[5];
  aE0 = *(const short8v*)(ap);
  aE1 = *(const short8v*)(ap + MSTR);
#pragma unroll
  for (int nt = 0; nt < 5; ++nt) bE[nt] = *(const short8v*)(bp + nt * 512);

  for (int kb = 0; kb < 32; kb += 2) {
    aO0 = *(const short8v*)(ap + (size_t)(kb + 1) * 512);
    aO1 = *(const short8v*)(ap + MSTR + (size_t)(kb + 1) * 512);
#pragma unroll
    for (int nt = 0; nt < 5; ++nt)
      bO[nt] = *(const short8v*)(bp + (size_t)((kb + 1) * 5 + nt) * 512);
#pragma unroll
    for (int nt = 0; nt < 5; ++nt) {
      mfma_b16(acc0[nt], aE0, bE[nt]);
      mfma_b16(acc1[nt], aE1, bE[nt]);
    }
    aE0 = *(const short8v*)(ap + (size_t)(kb + 2) * 512);
    aE1 = *(const short8v*)(ap + MSTR + (size_t)(kb + 2) * 512);
#pragma unroll
    for (int nt = 0; nt < 5; ++nt)
      bE[nt] = *(const short8v*)(bp + (size_t)((kb + 2) * 5 + nt) * 512);
#pragma unroll
    for (int nt = 0; nt < 5; ++nt) {
      mfma_b16(acc0[nt], aO0, bO[nt]);
      mfma_b16(acc1[nt], aO1, bO[nt]);
    }
  }
  asm volatile("s_nop 7\n\ts_nop 7\n\ts_nop 7" ::: "memory");

  // two-stage reduce: waves 4-7 fold into waves 0-3, then 4-way sum.
  auto red = reinterpret_cast<float(*)[64][40]>(smem);    // [4][64][40] = 40 KB
  if (w8 < 4) {
#pragma unroll
    for (int nt = 0; nt < 5; ++nt) {
      *(f32x4*)&red[w8][l][nt * 4]      = acc0[nt];
      *(f32x4*)&red[w8][l][20 + nt * 4] = acc1[nt];
    }
  }
  __syncthreads();
  if (w8 >= 4) {
#pragma unroll
    for (int nt = 0; nt < 5; ++nt) {
      f32x4 t0 = *(f32x4*)&red[w8 - 4][l][nt * 4];
      f32x4 t1 = *(f32x4*)&red[w8 - 4][l][20 + nt * 4];
      *(f32x4*)&red[w8 - 4][l][nt * 4]      = t0 + acc0[nt];
      *(f32x4*)&red[w8 - 4][l][20 + nt * 4] = t1 + acc1[nt];
    }
  }
  __syncthreads();
#pragma unroll
  for (int i = 0; i < 5; ++i) {
    int p = tid + i * 512;
    int r = p / 80, c = p % 80;
    int mtl = r >> 4, rl = r & 15;
    int ll = ((rl >> 2) << 4) | (c & 15);
    int slot = mtl * 20 + (((c >> 4) << 2) | (rl & 3));
    sv[i] = ((red[0][ll][slot] + red[1][ll][slot]) +
             red[2][ll][slot]) + red[3][ll][slot];
  }
  __syncthreads();                                        // smem reusable
}

// ---------------- hop1: X1 = A^T@XSin + XSin ; XS1 = dinv*X1 ; UtFout --------
__global__ __launch_bounds__(512, 1) void k_hop1(const ushort* __restrict__ adjF,
                                                 const ushort* __restrict__ UtFin,
                                                 const float* __restrict__ XSin,
                                                 const float* __restrict__ dinv,
                                                 float* __restrict__ X1,
                                                 float* __restrict__ XS1,
                                                 ushort* __restrict__ UtFout) {
  __shared__ __align__(16) float smem[10240];
  const int bid = blockIdx.x, tid = threadIdx.x;
  const int n0 = bid * 32;
  float sv[5];
  gemm_core2(adjF, UtFin, bid, tid, smem, sv);

  auto xs = reinterpret_cast<float(*)[80]>(smem);
#pragma unroll
  for (int i = 0; i < 5; ++i) {
    int p = tid + i * 512;
    size_t o = (size_t)n0 * CST + p;
    float x1 = XSin[o] + sv[i];
    X1[o] = x1;
    float z = dinv[n0 + p / 80] * x1;
    XS1[o] = z;
    xs[p / 80][p % 80] = z;
  }
  __syncthreads();
  for (int p = tid; p < 5 * 64; p += 512) {
    int nt = p >> 6, l = p & 63;
    short8v o8;
#pragma unroll
    for (int j = 0; j < 8; ++j)
      o8[j] = (short)f2bf(xs[8 * (l >> 4) + j][nt * 16 + (l & 15)]);
    *(short8v*)(UtFout + ((size_t)bid * 5 + nt) * 512 + l * 8) = o8;
  }
}

// ---------------- hop2+gates: X2 in LDS; sigmoid matmul; X0:=rh etc. ---------
__global__ __launch_bounds__(512, 1) void k_hop2g(const ushort* __restrict__ adjF,
    const ushort* __restrict__ UtFb, const float* __restrict__ XS1,
    const float* __restrict__ X0, const float* __restrict__ X1,
    const float* __restrict__ w_ru, const float* __restrict__ b_ru,
    const float* __restrict__ hx, const float* __restrict__ inp,
    const float* __restrict__ dinv,
    float* __restrict__ X0w, float* __restrict__ XS0w,
    ushort* __restrict__ UtFa, float* __restrict__ UG) {
  __shared__ __align__(16) float smem[10240];
  const int bid = blockIdx.x, tid = threadIdx.x;
  const int n0 = bid * 32;
  float sv[5];
  gemm_core2(adjF, UtFb, bid, tid, smem, sv);

  auto xr2 = reinterpret_cast<float(*)[80]>(smem);        // [32][80] = 2560
  float* xr01 = smem + 2560;                              // [2][32][68] = 4352
  float* rhq  = smem + 2560 + 4352;                       // [32][64] = 2048
#pragma unroll
  for (int i = 0; i < 5; ++i) {
    int p = tid + i * 512;
    size_t o = (size_t)n0 * CST + p;
    xr2[p / 80][p % 80] = 2.f * (XS1[o] + sv[i]) - X0[o];
  }
  for (int p = tid; p < 32 * 17; p += 512) {
    int nl = p / 17, c4 = (p % 17) * 4;
    size_t o = (size_t)(n0 + nl) * CST + c4;
    *(float4*)&xr01[nl * 68 + c4]            = *(const float4*)(X0 + o);
    *(float4*)&xr01[32 * 68 + nl * 68 + c4]  = *(const float4*)(X1 + o);
  }
  __syncthreads();

  const int nl = tid >> 4, og = tid & 15, o0 = og * 8;
  float acc[8];
#pragma unroll
  for (int j = 0; j < 8; ++j) acc[j] = b_ru[o0 + j];
  for (int c = 0; c < 66; ++c) {
    int f = (c < 64) ? (c + 2) : (c - 64);
    const float* wr = w_ru + (size_t)(f * 3) * 128 + o0;
    float xv[3];
    xv[0] = xr01[nl * 68 + c];
    xv[1] = xr01[32 * 68 + nl * 68 + c];
    xv[2] = xr2[nl][c];
#pragma unroll
    for (int m = 0; m < 3; ++m) {
      float wl[8];
      *(float4*)(wl)     = *(const float4*)(wr + m * 128);
      *(float4*)(wl + 4) = *(const float4*)(wr + m * 128 + 4);
#pragma unroll
      for (int j = 0; j < 8; ++j) acc[j] += xv[m] * wl[j];
    }
  }
  const int n = n0 + nl;
  const float dv = dinv[n];
  if (og < 8) {
#pragma unroll
    for (int j = 0; j < 8; ++j) {
      int o = o0 + j;
      float r = 1.f / (1.f + expf(-acc[j]));
      float rh = r * hx[n * 64 + o];
      X0w[(size_t)n * CST + o] = rh;
      float srh = dv * rh;
      XS0w[(size_t)n * CST + o] = srh;
      rhq[nl * 64 + o] = srh;
    }
  } else {
#pragma unroll
    for (int j = 0; j < 8; ++j)
      UG[n * 64 + (o0 - 64) + j] = 1.f / (1.f + expf(-acc[j]));
  }
  __syncthreads();
  for (int p = tid; p < 5 * 64; p += 512) {
    int nt = p >> 6, l = p & 63;
    short8v o8;
#pragma unroll
    for (int j = 0; j < 8; ++j) {
      int lr = 8 * (l >> 4) + j;
      int nn = n0 + lr;
      int c = nt * 16 + (l & 15);
      float v;
      if (c < 64)      v = rhq[lr * 64 + c];
      else if (c < 66) v = dinv[nn] * inp[nn * 2 + (c - 64)];
      else             v = 0.f;
      o8[j] = (short)f2bf(v);
    }
    *(short8v*)(UtFa + ((size_t)bid * 5 + nt) * 512 + l * 8) = o8;
  }
}

// ---------------- hop2+final: X2 in LDS; tanh matmul; output -----------------
__global__ __launch_bounds__(512, 1) void k_hop2f(const ushort* __restrict__ adjF,
    const ushort* __restrict__ UtFb, const float* __restrict__ XS1,
    const float* __restrict__ X0, const float* __restrict__ X1,
    const float* __restrict__ w_c, const float* __restrict__ b_c,
    const float* __restrict__ hx, const float* __restrict__ UG,
    float* __restrict__ out) {
  __shared__ __align__(16) float smem[10240];
  const int bid = blockIdx.x, tid = threadIdx.x;
  const int n0 = bid * 32;
  float sv[5];
  gemm_core2(adjF, UtFb, bid, tid, smem, sv);

  auto xr2 = reinterpret_cast<float(*)[80]>(smem);        // [32][80]
  float* xr01 = smem + 2560;                              // [2][32][68]
#pragma unroll
  for (int i = 0; i < 5; ++i) {
    int p = tid + i * 512;
    size_t o = (size_t)n0 * CST + p;
    xr2[p / 80][p % 80] = 2.f * (XS1[o] + sv[i]) - X0[o];
  }
  for (int p = tid; p < 32 * 17; p += 512) {
    int nl = p / 17, c4 = (p % 17) * 4;
    size_t o = (size_t)(n0 + nl) * CST + c4;
    *(float4*)&xr01[nl * 68 + c4]           = *(const float4*)(X0 + o);
    *(float4*)&xr01[32 * 68 + nl * 68 + c4] = *(const float4*)(X1 + o);
  }
  __syncthreads();

  const int nl = tid >> 4, ot = tid & 15, o0 = ot * 4;
  float acc[4];
#pragma unroll
  for (int j = 0; j < 4; ++j) acc[j] = b_c[o0 + j];
  for (int c = 0; c < 66; ++c) {
    int f = (c < 64) ? (c + 2) : (c - 64);
    float xv[3];
    xv[0] = xr01[nl * 68 + c];
    xv[1] = xr01[32 * 68 + nl * 68 + c];
    xv[2] = xr2[nl][c];
#pragma unroll
    for (int m = 0; m < 3; ++m) {
      float wl[4];
      *(float4*)(wl) = *(const float4*)(w_c + (size_t)(f * 3 + m) * 64 + o0);
#pragma unroll
      for (int j = 0; j < 4; ++j) acc[j] += xv[m] * wl[j];
    }
  }
  const int n = n0 + nl;
#pragma unroll
  for (int j = 0; j < 4; ++j) {
    int o = o0 + j;
    float cc = tanhf(acc[j]);
    float u = UG[n * 64 + o];
    float h = hx[n * 64 + o];
    out[n * 64 + o] = u * h + (1.f - u) * cc;
  }
}

// ---------------- launcher ----------------------------------------------------
extern "C" void kernel_launch(void* const* d_in, const int* in_sizes, int n_in,
                              void* d_out, int out_size, void* d_ws, size_t ws_size,
                              hipStream_t stream) {
  const float* inp  = (const float*)d_in[0];
  const float* hx   = (const float*)d_in[1];
  const float* adj  = (const float*)d_in[2];
  const float* w_ru = (const float*)d_in[3];
  const float* b_ru = (const float*)d_in[4];
  const float* w_c  = (const float*)d_in[5];
  const float* b_c  = (const float*)d_in[6];
  float* out = (float*)d_out;

  float* ws    = (float*)d_ws;
  float* dinv  = ws;                          // 8192
  float* dpart = ws + 8192;                   // 4*8192
  float* X0    = ws + 8192 + 4 * 8192;        // [N][80] each
  float* XS0   = X0 + NS;
  float* X1    = XS0 + NS;
  float* XS1   = X1 + NS;
  ushort* UtFa = (ushort*)(XS1 + NS);         // 1.25 MB
  ushort* UtFb = UtFa + UTFS;                 // 1.25 MB
  ushort* adjF = UtFb + UTFS;                 // 128 MB
  float*  UG   = (float*)(adjF + (size_t)512 * KBT * 512);  // [N][64] + OOB pad

  dim3 cg(KBT, MCH);

  k_conv <<<cg, 256, 0, stream>>>(adj, adjF, dpart);
  k_build<<<NN / 32, 256, 0, stream>>>(hx, inp, dpart, dinv, X0, XS0, UtFa);

  // gconv 1 (gates)
  k_hop1 <<<256, 512, 0, stream>>>(adjF, UtFa, XS0, dinv, X1, XS1, UtFb);
  k_hop2g<<<256, 512, 0, stream>>>(adjF, UtFb, XS1, X0, X1, w_ru, b_ru, hx, inp,
                                   dinv, X0, XS0, UtFa, UG);

  // gconv 2 (candidate)
  k_hop1 <<<256, 512, 0, stream>>>(adjF, UtFa, XS0, dinv, X1, XS1, UtFb);
  k_hop2f<<<256, 512, 0, stream>>>(adjF, UtFb, XS1, X0, X1, w_c, b_c, hx, UG, out);
}